// Round 9
// baseline (331.189 us; speedup 1.0000x reference)
//
#include <hip/hip_runtime.h>
#include <hip/hip_fp16.h>
#include <hip/hip_cooperative_groups.h>

namespace cg = cooperative_groups;

// Problem constants
// B=16, N=8, C=3, H=64, W=96; PRED_BITS=2; CONV_CH=16, FC=100, FMAP 16x24 (=384 pos, 6144 feat)
// Binary conv factorizes: conv(concat(si,sj),Wb) = conv(si,Wb[:, :3]) + conv(sj,Wb[:,3:])
// Conv as implicit-im2col MFMA GEMM; pair expansion fused into FC1 GEMM staging.
// R9: persistent cooperative kernel (grid=256, 1 block/CU guaranteed co-resident)
//     with error-checked fallback to the proven R7 3-kernel pipeline.

typedef __attribute__((ext_vector_type(8))) _Float16 f16x8;
typedef __attribute__((ext_vector_type(4))) float f32x4;

__device__ inline unsigned short h16u(float x) {
    __half h = __float2half(x);
    return __builtin_bit_cast(unsigned short, h);
}

// packed f16 relu(f + s) on 8 halves (v_pk_add_f16 + v_pk_max_f16)
__device__ inline uint4 pair_relu4(uint4 f, uint4 s) {
    f16x8 a = __builtin_bit_cast(f16x8, f);
    f16x8 b = __builtin_bit_cast(f16x8, s);
    const f16x8 z = {0, 0, 0, 0, 0, 0, 0, 0};
    f16x8 r = a + b;
    r = __builtin_elementwise_max(r, z);
    return __builtin_bit_cast(uint4, r);
}

#define CL_STRIDE 106
#define CL_CH (36 * CL_STRIDE)   // 3816 shorts per channel plane
#define SH_SHORTS 13824          // 27,648 B block LDS (union of all phases)

// ---------------------------------------------------------------------------
// Item A: conv over half an image (item 0..767) or W2 transpose tile
// (item 768..863). Identical math to R7's conv_prep_kernel.
// ---------------------------------------------------------------------------
__device__ void conv_item(
    int item, int tid, unsigned short* sh,
    const float* s0, const float* s1, const float* s2,
    const float* Wcu, const float* Wcb,
    const float* bcu, const float* bcb,
    const float* W2b, const float* W2u,
    unsigned short* Au, unsigned short* yfb, unsigned short* ysb,
    unsigned short* Btb, unsigned short* Btu)
{
    if (item >= 768) {
        // ---- W2 transpose: Bt[f][k] = W2[k][f], f padded to 128 ----
        const int bx2 = item - 768;
        const int arr = bx2 / 48;
        const int k0 = (bx2 % 48) * 128;
        const float* W2 = arr ? W2u : W2b;
        unsigned short* Bt = arr ? Btu : Btb;
#pragma unroll
        for (int p = 0; p < 2; ++p) {
            const int kk0 = p * 64;
            __syncthreads();
            for (int t = tid; t < 64 * 128; t += 256) {
                int kk = t >> 7, f = t & 127;
                float v = (f < 100) ? W2[(long)(k0 + kk0 + kk) * 100 + f] : 0.f;
                sh[kk * 130 + f] = h16u(v);
            }
            __syncthreads();
            for (int t = tid; t < 64 * 128; t += 256) {
                int f = t >> 6, kk = t & 63;
                Bt[(long)f * 6144 + k0 + kk0 + kk] = sh[kk * 130 + f];
            }
        }
        return;
    }

    // ---- conv over half an image ----
    const int si  = item >> 8;
    const int rem = item & 255;
    const int img = rem >> 1;
    const int h   = rem & 1;
    const float* simg = (si == 0 ? s0 : (si == 1 ? s1 : s2)) + (long)img * 18432;

    const int lane = tid & 63;
    const int w    = tid >> 6;
    const int quad = lane >> 4;
    const int lcol = lane & 15;

    // Phase 0: cooperative conv-weight fragment build (coalesced float4 reads).
    {
        unsigned* d = (unsigned*)sh;
        const float4* Wu4 = (const float4*)Wcu;          // 768 float4
        for (int l4 = tid; l4 < 768; l4 += 256) {
            int l = l4 * 4, ch = l / 192, e = l % 192;
            int g = (e >> 5) * 3;                        // nt = 0
            int bi = ((g * 64 + ((e >> 3) & 3) * 16 + ch) * 8 + (e & 7)) >> 1;
            float4 v = Wu4[l4];
            d[bi]     = (unsigned)h16u(v.x) | ((unsigned)h16u(v.y) << 16);
            d[bi + 1] = (unsigned)h16u(v.z) | ((unsigned)h16u(v.w) << 16);
        }
        const float4* Wb4 = (const float4*)Wcb;          // 1536 float4
        for (int l4 = tid; l4 < 1536; l4 += 256) {
            int l = l4 * 4, ch = l / 384, r = l % 384;
            int nt = (r < 192) ? 1 : 2, e = r % 192;
            int g = (e >> 5) * 3 + nt;
            int bi = ((g * 64 + ((e >> 3) & 3) * 16 + ch) * 8 + (e & 7)) >> 1;
            float4 v = Wb4[l4];
            d[bi]     = (unsigned)h16u(v.x) | ((unsigned)h16u(v.y) << 16);
            d[bi + 1] = (unsigned)h16u(v.z) | ((unsigned)h16u(v.w) << 16);
        }
    }
    __syncthreads();

    f16x8 bw[6][3];
#pragma unroll
    for (int t6 = 0; t6 < 6; ++t6)
#pragma unroll
        for (int nt = 0; nt < 3; ++nt)
            bw[t6][nt] = *(const f16x8*)(sh + ((t6 * 3 + nt) * 64 + lane) * 8);
    __syncthreads();   // fragments now in registers; LDS free for image tile

    // Phase 1: zero-fill image tile (borders must be 0)
    for (int t = tid; t < (3 * CL_CH) / 2; t += 256)
        ((unsigned*)sh)[t] = 0u;
    __syncthreads();

    // Phase 2: stage image as f16 (LDS row r <-> input row iy = h*32 + r - 2)
    const int y0 = h * 32;
    for (int t = tid; t < 3 * 36 * 24; t += 256) {
        int c = t / 864, rq = t % 864, r = rq / 24, q = rq % 24;
        int iy = y0 + r - 2;
        if (iy >= 0 && iy < 64) {
            float4 v = *((const float4*)(simg + c * 6144 + iy * 96) + q);
            unsigned lo = (unsigned)h16u(v.x) | ((unsigned)h16u(v.y) << 16);
            unsigned hi = (unsigned)h16u(v.z) | ((unsigned)h16u(v.w) << 16);
            unsigned* dst = (unsigned*)(sh + c * CL_CH + r * CL_STRIDE + q * 4 + 4);
            dst[0] = lo; dst[1] = hi;
        }
    }
    __syncthreads();

    const float bu = bcu[lcol];
    const float bb = bcb[lcol];

    // Phase 3: MFMA. Hold all 9 accumulators (3 m-tiles x 3 outputs).
    f32x4 accs[3][3];
#pragma unroll
    for (int mi = 0; mi < 3; ++mi)
#pragma unroll
        for (int nt = 0; nt < 3; ++nt) accs[mi][nt] = (f32x4){0.f, 0.f, 0.f, 0.f};

#pragma unroll
    for (int mi = 0; mi < 3; ++mi) {
        const int mt = w * 3 + mi;           // m-tile 0..11
        const int p  = mt * 16 + lcol;       // this lane's A-row (position)
        const int oyl = p / 24, ox = p % 24;
#pragma unroll
        for (int t6 = 0; t6 < 6; ++t6) {
            int g  = t6 * 4 + quad;          // tap group: c = g/8, ky = g%8
            int c  = g >> 3, ky = g & 7;
            const unsigned* lp = (const unsigned*)(sh + c * CL_CH + (oyl * 4 + ky) * CL_STRIDE + ox * 4 + 2);
            f16x8 afr;
            unsigned* ap = (unsigned*)&afr;
            ap[0] = lp[0]; ap[1] = lp[1]; ap[2] = lp[2]; ap[3] = lp[3];
            accs[mi][0] = __builtin_amdgcn_mfma_f32_16x16x32_f16(afr, bw[t6][0], accs[mi][0], 0, 0, 0);
            accs[mi][1] = __builtin_amdgcn_mfma_f32_16x16x32_f16(afr, bw[t6][1], accs[mi][1], 0, 0, 0);
            accs[mi][2] = __builtin_amdgcn_mfma_f32_16x16x32_f16(afr, bw[t6][2], accs[mi][2], 0, 0, 0);
        }
    }
    __syncthreads();   // all image reads done; LDS reused for output transpose

    // Phase 4: write acc -> LDS (stride 200 halves; <=2-way banks).
#pragma unroll
    for (int mi = 0; mi < 3; ++mi) {
        const int base = (w * 3 + mi) * 16 + quad * 4;   // pos 0..191
#pragma unroll
        for (int nt = 0; nt < 3; ++nt) {
            ushort4 o;
#pragma unroll
            for (int reg = 0; reg < 4; ++reg) {
                float v = accs[mi][nt][reg];
                if (nt == 0) { v += bu; v = v > 0.f ? v : 0.f; }
                else if (nt == 1) v += bb;
                ((unsigned short*)&o)[reg] = h16u(v);
            }
            *(ushort4*)(sh + (nt * 16 + lcol) * 200 + base) = o;
        }
    }
    __syncthreads();

    // Phase 5: cooperative coalesced stores (1152 uint4 per block).
    const long im = (long)si * 128 + img;
    unsigned short* outp0 = Au  + im * 6144;
    unsigned short* outp1 = yfb + im * 6144;
    unsigned short* outp2 = ysb + im * 6144;
    for (int t = tid; t < 1152; t += 256) {
        int nt = t / 384, r = t % 384, ch = r / 24, q = r % 24;
        uint4 v = *(const uint4*)(sh + (nt * 16 + ch) * 200 + q * 8);
        unsigned short* op = (nt == 0) ? outp0 : (nt == 1) ? outp1 : outp2;
        *(uint4*)(op + ch * 384 + h * 192 + q * 8) = v;
    }
}

// ---------------------------------------------------------------------------
// Item B: one GEMM tile (tile 0..431): fused expand + split-K f16 MFMA.
// ---------------------------------------------------------------------------
__device__ void gemm_tile(
    int tile, int tid, unsigned short* sh,
    const unsigned short* yfb, const unsigned short* ysb,
    const unsigned short* Au,
    const unsigned short* Btb, const unsigned short* Btu,
    __half* partial)
{
    unsigned short* lsA = sh;             // 64 x 72
    unsigned short* lsB = sh + 64 * 72;   // 128 x 72
    const int mt = tile % 54;
    const int kc = tile / 54;             // 0..7

    const int lane = tid & 63;
    const int w  = tid >> 6;
    const int wr = w & 1;
    const int wc = w >> 1;
    const int quad = lane >> 4;
    const int lcol = lane & 15;

    f32x4 acc[2][4];
#pragma unroll
    for (int i = 0; i < 2; ++i)
#pragma unroll
        for (int j = 0; j < 4; ++j) acc[i][j] = (f32x4){0.f, 0.f, 0.f, 0.f};

    const int ra = tid >> 2, qa = tid & 3;
    const bool fused = (mt < 48);
    const unsigned short *pf, *ps = nullptr;
    if (fused) {
        int g = mt * 64 + ra;                // global binary pair row
        int si = g >> 10, gs = g & 1023;
        int b = gs >> 6, i = (gs >> 3) & 7, j = gs & 7;
        pf = yfb + (long)(si * 128 + b * 8 + i) * 6144;
        ps = ysb + (long)(si * 128 + b * 8 + j) * 6144;
    } else {
        pf = Au + (long)((mt - 48) * 64 + ra) * 6144;
    }
    const unsigned short* Bt = fused ? Btb : Btu;
    const int rb = tid >> 1, hb = tid & 1;
    const long brow = (long)rb * 6144;
    const int kbase0 = kc * 768;

    for (int it = 0; it < 12; ++it) {
        const int kb = kbase0 + it * 64;
        const uint4* gbp = (const uint4*)(Bt + brow + kb + hb * 32);
        uint4 b0 = gbp[0], b1 = gbp[1], b2 = gbp[2], b3 = gbp[3];
        const uint4* gf = (const uint4*)(pf + kb + qa * 16);
        uint4 f0 = gf[0], f1 = gf[1];
        if (fused) {
            const uint4* gs2 = (const uint4*)(ps + kb + qa * 16);
            f0 = pair_relu4(f0, gs2[0]);
            f1 = pair_relu4(f1, gs2[1]);
        }
        __syncthreads();   // previous iter's (or tile's) LDS reads done
        uint4* da = (uint4*)(lsA + ra * 72 + qa * 16);
        uint4* db = (uint4*)(lsB + rb * 72 + hb * 32);
        da[0] = f0; da[1] = f1;
        db[0] = b0; db[1] = b1; db[2] = b2; db[3] = b3;
        __syncthreads();
#pragma unroll
        for (int ks = 0; ks < 2; ++ks) {
            f16x8 af[2], bfr[4];
#pragma unroll
            for (int t = 0; t < 2; ++t)
                af[t] = *(const f16x8*)(lsA + (wr * 32 + t * 16 + lcol) * 72 + ks * 32 + quad * 8);
#pragma unroll
            for (int t = 0; t < 4; ++t)
                bfr[t] = *(const f16x8*)(lsB + (wc * 64 + t * 16 + lcol) * 72 + ks * 32 + quad * 8);
#pragma unroll
            for (int i = 0; i < 2; ++i)
#pragma unroll
                for (int j = 0; j < 4; ++j)
                    acc[i][j] = __builtin_amdgcn_mfma_f32_16x16x32_f16(af[i], bfr[j], acc[i][j], 0, 0, 0);
        }
    }

    __half* op = partial + (long)(kc * 54 + mt) * 8192;
#pragma unroll
    for (int i = 0; i < 2; ++i)
#pragma unroll
        for (int j = 0; j < 4; ++j)
#pragma unroll
            for (int reg = 0; reg < 4; ++reg) {
                int rr = wr * 32 + i * 16 + quad * 4 + reg;
                int cc = wc * 64 + j * 16 + lcol;
                op[rr * 128 + cc] = __float2half(acc[i][j][reg]);
            }
}

// ---------------------------------------------------------------------------
// Item C: one destination position (16-lane group): reduce + FC2 + gumbel +
// compaction.
// ---------------------------------------------------------------------------
__device__ void head_task(
    int dp, int c,
    const __half* partial,
    const float* b2b, const float* b2u,
    const float* W3b, const float* b3b,
    const float* W3u, const float* b3u,
    const float* gb, const float* gu,
    const int* nobj, const float* temp_p,
    float* out)
{
    const bool un = dp >= 3072;
    int srcrow, validf;
    long gidx, oidx;
    if (!un) {
        int si = dp / 1024, rem = dp % 1024;
        int b = rem >> 6, p = rem & 63;
        int n = nobj[b];
        int ns = n > 0 ? n : 1;
        int k = (p / ns) * 8 + (p % ns);
        validf = p < n * n;
        int kk = k < 63 ? k : 63;
        srcrow = si * 1024 + b * 64 + kk;
        gidx = (long)srcrow * 2;                 // gumbel uses SOURCE index
        oidx = (long)si * 2048 + (b * 64 + p) * 2;
    } else {
        int r = dp - 3072;
        int si = r / 128, q = r % 128;
        int b = q >> 3, i = q & 7;
        srcrow = 3072 + r;
        validf = i < nobj[b];
        gidx = (long)si * 256 + q * 2;
        oidx = 6144 + (long)si * 256 + q * 2;
    }

    const float* b2 = un ? b2u : b2b;
    const float* W3 = un ? W3u : W3b;
    const int mt2 = srcrow >> 6, rr = srcrow & 63;
    float l0 = 0.f, l1 = 0.f;
    for (int f = c; f < 100; f += 16) {
        float s = b2[f];
#pragma unroll
        for (int kc2 = 0; kc2 < 8; ++kc2)
            s += __half2float(partial[((long)(kc2 * 54 + mt2) * 64 + rr) * 128 + f]);
        float hv = s > 0.f ? s : 0.f;
        l0 = fmaf(hv, W3[f * 2],     l0);
        l1 = fmaf(hv, W3[f * 2 + 1], l1);
    }
#pragma unroll
    for (int off = 8; off >= 1; off >>= 1) {
        l0 += __shfl_xor(l0, off);
        l1 += __shfl_xor(l1, off);
    }
    if (c == 0) {
        const float* b3 = un ? b3u : b3b;
        const float* g = (un ? gu : gb) + gidx;
        float d = ((l0 + b3[0] + g[0]) - (l1 + b3[1] + g[1])) / temp_p[0];
        float p0 = 1.f / (1.f + expf(-d));
        out[oidx]     = validf ? p0 : 0.f;
        out[oidx + 1] = validf ? 1.f - p0 : 0.f;
    }
}

// ---------------------------------------------------------------------------
// Persistent cooperative kernel: grid = 256 (1 block/CU — co-residency
// trivially satisfied). Phase loops cover 864 conv items / 432 GEMM tiles /
// 3456 head positions.
// ---------------------------------------------------------------------------
__global__ __launch_bounds__(256) void fused_all(
    const float* s0, const float* s1, const float* s2,
    const float* Wcu, const float* Wcb,
    const float* bcu, const float* bcb,
    const float* W2b, const float* W2u,
    unsigned short* Au, unsigned short* yfb, unsigned short* ysb,
    unsigned short* Btb, unsigned short* Btu,
    __half* partial,
    const float* b2b, const float* b2u,
    const float* W3b, const float* b3b,
    const float* W3u, const float* b3u,
    const float* gb, const float* gu,
    const int* nobj, const float* temp_p,
    float* out)
{
    __shared__ __align__(16) unsigned short sh[SH_SHORTS];
    const int bx  = blockIdx.x;
    const int tid = threadIdx.x;
    cg::grid_group grid = cg::this_grid();

    for (int item = bx; item < 864; item += 256) {
        conv_item(item, tid, sh, s0, s1, s2, Wcu, Wcb, bcu, bcb, W2b, W2u,
                  Au, yfb, ysb, Btb, Btu);
        __syncthreads();
    }

    __threadfence();
    grid.sync();

    for (int t = bx; t < 432; t += 256)
        gemm_tile(t, tid, sh, yfb, ysb, Au, Btb, Btu, partial);

    __threadfence();
    grid.sync();

    {
        const int dp = bx * 16 + (tid >> 4);
        if (dp < 3456)
            head_task(dp, tid & 15, partial, b2b, b2u, W3b, b3b, W3u, b3u,
                      gb, gu, nobj, temp_p, out);
    }
}

// ---------------------------------------------------------------------------
// Fallback separate kernels (identical math, R7-proven structure).
// ---------------------------------------------------------------------------
__global__ __launch_bounds__(256) void conv_sep(
    const float* __restrict__ s0, const float* __restrict__ s1, const float* __restrict__ s2,
    const float* __restrict__ Wcu, const float* __restrict__ Wcb,
    const float* __restrict__ bcu, const float* __restrict__ bcb,
    const float* __restrict__ W2b, const float* __restrict__ W2u,
    unsigned short* __restrict__ Au, unsigned short* __restrict__ yfb,
    unsigned short* __restrict__ ysb,
    unsigned short* __restrict__ Btb, unsigned short* __restrict__ Btu)
{
    __shared__ __align__(16) unsigned short sh[SH_SHORTS];
    conv_item(blockIdx.x, threadIdx.x, sh, s0, s1, s2, Wcu, Wcb, bcu, bcb,
              W2b, W2u, Au, yfb, ysb, Btb, Btu);
}

__global__ __launch_bounds__(256) void gemm_sep(
    const unsigned short* __restrict__ yfb, const unsigned short* __restrict__ ysb,
    const unsigned short* __restrict__ Au,
    const unsigned short* __restrict__ Btb, const unsigned short* __restrict__ Btu,
    __half* __restrict__ partial)
{
    __shared__ __align__(16) unsigned short sh[SH_SHORTS];
    gemm_tile(blockIdx.x, threadIdx.x, sh, yfb, ysb, Au, Btb, Btu, partial);
}

__global__ __launch_bounds__(256) void head_sep(
    const __half* __restrict__ partial,
    const float* __restrict__ b2b, const float* __restrict__ b2u,
    const float* __restrict__ W3b, const float* __restrict__ b3b,
    const float* __restrict__ W3u, const float* __restrict__ b3u,
    const float* __restrict__ gb, const float* __restrict__ gu,
    const int* __restrict__ nobj, const float* __restrict__ temp_p,
    float* __restrict__ out)
{
    const int dp = blockIdx.x * 16 + (threadIdx.x >> 4);
    if (dp < 3456)
        head_task(dp, threadIdx.x & 15, partial, b2b, b2u, W3b, b3b, W3u, b3u,
                  gb, gu, nobj, temp_p, out);
}

// ---------------------------------------------------------------------------
// Workspace layout (bytes)
// ---------------------------------------------------------------------------
static const size_t YFB_OFF  = 0;                          // 384*6144 f16 = 4,718,592
static const size_t YSB_OFF  = 4718592;                    // 4,718,592
static const size_t AU_OFF   = 9437184;                    // 4,718,592
static const size_t BTB_OFF  = 14155776;                   // 1,572,864
static const size_t BTU_OFF  = 15728640;                   // 1,572,864
static const size_t PART_OFF = 17301504;                   // 8*54*64*128 f16 = 7,077,888
// total = 24,379,392 bytes

extern "C" void kernel_launch(void* const* d_in, const int* in_sizes, int n_in,
                              void* d_out, int out_size, void* d_ws, size_t ws_size,
                              hipStream_t stream) {
    const float* state   = (const float*)d_in[0];
    const float* state_n = (const float*)d_in[1];
    const float* state_t = (const float*)d_in[2];
    const int*   n_obj   = (const int*)  d_in[3];
    const float* temp    = (const float*)d_in[4];
    const float* g_un    = (const float*)d_in[5];
    const float* g_bin   = (const float*)d_in[6];
    const float* Wc_u    = (const float*)d_in[7];
    const float* bc_u    = (const float*)d_in[8];
    const float* W2_u    = (const float*)d_in[9];
    const float* b2_u    = (const float*)d_in[10];
    const float* W3_u    = (const float*)d_in[11];
    const float* b3_u    = (const float*)d_in[12];
    const float* Wc_b    = (const float*)d_in[13];
    const float* bc_b    = (const float*)d_in[14];
    const float* W2_b    = (const float*)d_in[15];
    const float* b2_b    = (const float*)d_in[16];
    const float* W3_b    = (const float*)d_in[17];
    const float* b3_b    = (const float*)d_in[18];

    char* ws = (char*)d_ws;
    unsigned short* yfb  = (unsigned short*)(ws + YFB_OFF);
    unsigned short* ysb  = (unsigned short*)(ws + YSB_OFF);
    unsigned short* Au   = (unsigned short*)(ws + AU_OFF);
    unsigned short* Btb  = (unsigned short*)(ws + BTB_OFF);
    unsigned short* Btu  = (unsigned short*)(ws + BTU_OFF);
    __half*         prt  = (__half*)(ws + PART_OFF);
    float*          out  = (float*)d_out;

    void* args[] = {
        (void*)&state, (void*)&state_n, (void*)&state_t,
        (void*)&Wc_u, (void*)&Wc_b, (void*)&bc_u, (void*)&bc_b,
        (void*)&W2_b, (void*)&W2_u,
        (void*)&Au, (void*)&yfb, (void*)&ysb,
        (void*)&Btb, (void*)&Btu,
        (void*)&prt,
        (void*)&b2_b, (void*)&b2_u,
        (void*)&W3_b, (void*)&b3_b,
        (void*)&W3_u, (void*)&b3_u,
        (void*)&g_bin, (void*)&g_un,
        (void*)&n_obj, (void*)&temp,
        (void*)&out
    };
    hipError_t err = hipLaunchCooperativeKernel((const void*)fused_all,
                                                dim3(256), dim3(256),
                                                args, 0, stream);
    if (err != hipSuccess) {
        // Fallback: proven 3-kernel pipeline (identical math).
        hipLaunchKernelGGL(conv_sep, dim3(864), dim3(256), 0, stream,
                           state, state_n, state_t, Wc_u, Wc_b, bc_u, bc_b,
                           W2_b, W2_u, Au, yfb, ysb, Btb, Btu);
        hipLaunchKernelGGL(gemm_sep, dim3(432), dim3(256), 0, stream,
                           yfb, ysb, Au, Btb, Btu, prt);
        hipLaunchKernelGGL(head_sep, dim3(216), dim3(256), 0, stream,
                           prt, b2_b, b2_u, W3_b, b3_b, W3_u, b3_u,
                           g_bin, g_un, n_obj, temp, out);
    }
}

// Round 10
// 147.500 us; speedup vs baseline: 2.2454x; 2.2454x over previous
//
#include <hip/hip_runtime.h>
#include <hip/hip_fp16.h>

// Problem constants
// B=16, N=8, C=3, H=64, W=96; PRED_BITS=2; CONV_CH=16, FC=100, FMAP 16x24 (=384 pos, 6144 feat)
// Binary conv factorizes: conv(concat(si,sj),Wb) = conv(si,Wb[:, :3]) + conv(sj,Wb[:,3:])
// Conv as implicit-im2col MFMA GEMM: M=positions, N=48 out-ch, K=192 taps.
// Pair expansion relu(yf_i + ys_j) fused into FC1 GEMM staging (A never materialized).
// 3-kernel pipeline: [conv+W2-transpose] -> [fused expand+FC1 GEMM] -> [reduce+FC2+gumbel+compact]
// R4 lesson: per-thread uncoalesced weight loads serialize L1 -> cooperative LDS build.
// R9 lesson: persistent cooperative kernel (1 block/CU) loses 2x to occupancy — keep 3 launches.
// R10: software-pipeline the GEMM K-loop (prefetch next iter's globals before MFMA).

typedef __attribute__((ext_vector_type(8))) _Float16 f16x8;
typedef __attribute__((ext_vector_type(4))) float f32x4;

__device__ inline unsigned short h16u(float x) {
    __half h = __float2half(x);
    return __builtin_bit_cast(unsigned short, h);
}

// packed f16 relu(f + s) on 8 halves (v_pk_add_f16 + v_pk_max_f16)
__device__ inline uint4 pair_relu4(uint4 f, uint4 s) {
    f16x8 a = __builtin_bit_cast(f16x8, f);
    f16x8 b = __builtin_bit_cast(f16x8, s);
    const f16x8 z = {0, 0, 0, 0, 0, 0, 0, 0};
    f16x8 r = a + b;
    r = __builtin_elementwise_max(r, z);
    return __builtin_bit_cast(uint4, r);
}

// ---------------------------------------------------------------------------
// Kernel 1: MFMA implicit-im2col conv (blocks 0..767, half-image each) +
// W2 transpose to Bt[f][k] f16 (blocks 768..863, 64-row double-pass tile).
// Identical to R7 (proven).
// ---------------------------------------------------------------------------
#define CL_STRIDE 106
#define CL_CH (36 * CL_STRIDE)   // 3816 shorts per channel plane
__global__ __launch_bounds__(256) void conv_prep_kernel(
    const float* __restrict__ s0, const float* __restrict__ s1, const float* __restrict__ s2,
    const float* __restrict__ Wcu, const float* __restrict__ Wcb,
    const float* __restrict__ bcu, const float* __restrict__ bcb,
    const float* __restrict__ W2b, const float* __restrict__ W2u,
    unsigned short* __restrict__ Au, unsigned short* __restrict__ yfb,
    unsigned short* __restrict__ ysb,
    unsigned short* __restrict__ Btb, unsigned short* __restrict__ Btu)
{
    __shared__ __align__(16) unsigned short sh[3 * CL_CH];   // 11448 shorts = 22,896 B
    const int bx  = blockIdx.x;
    const int tid = threadIdx.x;

    if (bx >= 768) {
        // ---- W2 transpose: Bt[f][k] = W2[k][f], f padded to 128 ----
        const int bx2 = bx - 768;
        const int arr = bx2 / 48;
        const int k0 = (bx2 % 48) * 128;
        const float* W2 = arr ? W2u : W2b;
        unsigned short* Bt = arr ? Btu : Btb;
#pragma unroll
        for (int p = 0; p < 2; ++p) {
            const int kk0 = p * 64;
            __syncthreads();
            for (int t = tid; t < 64 * 128; t += 256) {
                int kk = t >> 7, f = t & 127;
                float v = (f < 100) ? W2[(long)(k0 + kk0 + kk) * 100 + f] : 0.f;
                sh[kk * 130 + f] = h16u(v);
            }
            __syncthreads();
            for (int t = tid; t < 64 * 128; t += 256) {
                int f = t >> 6, kk = t & 63;
                Bt[(long)f * 6144 + k0 + kk0 + kk] = sh[kk * 130 + f];
            }
        }
        return;
    }

    // ---- conv over half an image ----
    const int si  = bx >> 8;
    const int rem = bx & 255;
    const int img = rem >> 1;
    const int h   = rem & 1;
    const float* simg = (si == 0 ? s0 : (si == 1 ? s1 : s2)) + (long)img * 18432;

    const int lane = tid & 63;
    const int w    = tid >> 6;
    const int quad = lane >> 4;
    const int lcol = lane & 15;

    // Phase 0: cooperative conv-weight fragment build (coalesced float4 reads).
    {
        unsigned* d = (unsigned*)sh;
        const float4* Wu4 = (const float4*)Wcu;          // 768 float4
        for (int l4 = tid; l4 < 768; l4 += 256) {
            int l = l4 * 4, ch = l / 192, e = l % 192;
            int g = (e >> 5) * 3;                        // nt = 0
            int bi = ((g * 64 + ((e >> 3) & 3) * 16 + ch) * 8 + (e & 7)) >> 1;
            float4 v = Wu4[l4];
            d[bi]     = (unsigned)h16u(v.x) | ((unsigned)h16u(v.y) << 16);
            d[bi + 1] = (unsigned)h16u(v.z) | ((unsigned)h16u(v.w) << 16);
        }
        const float4* Wb4 = (const float4*)Wcb;          // 1536 float4
        for (int l4 = tid; l4 < 1536; l4 += 256) {
            int l = l4 * 4, ch = l / 384, r = l % 384;
            int nt = (r < 192) ? 1 : 2, e = r % 192;
            int g = (e >> 5) * 3 + nt;
            int bi = ((g * 64 + ((e >> 3) & 3) * 16 + ch) * 8 + (e & 7)) >> 1;
            float4 v = Wb4[l4];
            d[bi]     = (unsigned)h16u(v.x) | ((unsigned)h16u(v.y) << 16);
            d[bi + 1] = (unsigned)h16u(v.z) | ((unsigned)h16u(v.w) << 16);
        }
    }
    __syncthreads();

    f16x8 bw[6][3];
#pragma unroll
    for (int t6 = 0; t6 < 6; ++t6)
#pragma unroll
        for (int nt = 0; nt < 3; ++nt)
            bw[t6][nt] = *(const f16x8*)(sh + ((t6 * 3 + nt) * 64 + lane) * 8);
    __syncthreads();   // fragments now in registers; LDS free for image tile

    // Phase 1: zero-fill image tile (borders must be 0)
    for (int t = tid; t < (3 * CL_CH) / 2; t += 256)
        ((unsigned*)sh)[t] = 0u;
    __syncthreads();

    // Phase 2: stage image as f16 (LDS row r <-> input row iy = h*32 + r - 2)
    const int y0 = h * 32;
    for (int t = tid; t < 3 * 36 * 24; t += 256) {
        int c = t / 864, rq = t % 864, r = rq / 24, q = rq % 24;
        int iy = y0 + r - 2;
        if (iy >= 0 && iy < 64) {
            float4 v = *((const float4*)(simg + c * 6144 + iy * 96) + q);
            unsigned lo = (unsigned)h16u(v.x) | ((unsigned)h16u(v.y) << 16);
            unsigned hi = (unsigned)h16u(v.z) | ((unsigned)h16u(v.w) << 16);
            unsigned* dst = (unsigned*)(sh + c * CL_CH + r * CL_STRIDE + q * 4 + 4);
            dst[0] = lo; dst[1] = hi;
        }
    }
    __syncthreads();

    const float bu = bcu[lcol];
    const float bb = bcb[lcol];

    // Phase 3: MFMA. Hold all 9 accumulators (3 m-tiles x 3 outputs).
    f32x4 accs[3][3];
#pragma unroll
    for (int mi = 0; mi < 3; ++mi)
#pragma unroll
        for (int nt = 0; nt < 3; ++nt) accs[mi][nt] = (f32x4){0.f, 0.f, 0.f, 0.f};

#pragma unroll
    for (int mi = 0; mi < 3; ++mi) {
        const int mt = w * 3 + mi;           // m-tile 0..11
        const int p  = mt * 16 + lcol;       // this lane's A-row (position)
        const int oyl = p / 24, ox = p % 24;
#pragma unroll
        for (int t6 = 0; t6 < 6; ++t6) {
            int g  = t6 * 4 + quad;          // tap group: c = g/8, ky = g%8
            int c  = g >> 3, ky = g & 7;
            const unsigned* lp = (const unsigned*)(sh + c * CL_CH + (oyl * 4 + ky) * CL_STRIDE + ox * 4 + 2);
            f16x8 afr;
            unsigned* ap = (unsigned*)&afr;
            ap[0] = lp[0]; ap[1] = lp[1]; ap[2] = lp[2]; ap[3] = lp[3];
            accs[mi][0] = __builtin_amdgcn_mfma_f32_16x16x32_f16(afr, bw[t6][0], accs[mi][0], 0, 0, 0);
            accs[mi][1] = __builtin_amdgcn_mfma_f32_16x16x32_f16(afr, bw[t6][1], accs[mi][1], 0, 0, 0);
            accs[mi][2] = __builtin_amdgcn_mfma_f32_16x16x32_f16(afr, bw[t6][2], accs[mi][2], 0, 0, 0);
        }
    }
    __syncthreads();   // all image reads done; LDS reused for output transpose

    // Phase 4: write acc -> LDS (stride 200 halves; <=2-way banks).
#pragma unroll
    for (int mi = 0; mi < 3; ++mi) {
        const int base = (w * 3 + mi) * 16 + quad * 4;   // pos 0..191
#pragma unroll
        for (int nt = 0; nt < 3; ++nt) {
            ushort4 o;
#pragma unroll
            for (int reg = 0; reg < 4; ++reg) {
                float v = accs[mi][nt][reg];
                if (nt == 0) { v += bu; v = v > 0.f ? v : 0.f; }
                else if (nt == 1) v += bb;
                ((unsigned short*)&o)[reg] = h16u(v);
            }
            *(ushort4*)(sh + (nt * 16 + lcol) * 200 + base) = o;
        }
    }
    __syncthreads();

    // Phase 5: cooperative coalesced stores (1152 uint4 per block).
    const long im = (long)si * 128 + img;
    unsigned short* outp0 = Au  + im * 6144;
    unsigned short* outp1 = yfb + im * 6144;
    unsigned short* outp2 = ysb + im * 6144;
    for (int t = tid; t < 1152; t += 256) {
        int nt = t / 384, r = t % 384, ch = r / 24, q = r % 24;
        uint4 v = *(const uint4*)(sh + (nt * 16 + ch) * 200 + q * 8);
        unsigned short* op = (nt == 0) ? outp0 : (nt == 1) ? outp1 : outp2;
        *(uint4*)(op + ch * 384 + h * 192 + q * 8) = v;
    }
}

// ---------------------------------------------------------------------------
// Kernel 2: fused expand + split-K f16 MFMA GEMM, SOFTWARE-PIPELINED.
// M = 3456 as 54 tiles of 64 rows (48 binary + 6 unary), N = 128 (100 used),
// K = 6144 in 8 chunks. Binary A-tiles built on the fly from yfb/ysb.
// Prefetch: iter k+1's global loads issue right after the LDS-write barrier,
// overlapping MFMA + both barriers; consumed at the top of the next iter.
// ---------------------------------------------------------------------------
__global__ __launch_bounds__(256) void gemm_kernel(
    const unsigned short* __restrict__ yfb, const unsigned short* __restrict__ ysb,
    const unsigned short* __restrict__ Au,
    const unsigned short* __restrict__ Btb, const unsigned short* __restrict__ Btu,
    __half* __restrict__ partial)
{
    const int tid = threadIdx.x;
    const int mt = blockIdx.x % 54;
    const int kc = blockIdx.x / 54;      // 0..7

    __shared__ __align__(16) unsigned short lsA[64 * 72];
    __shared__ __align__(16) unsigned short lsB[128 * 72];

    const int lane = tid & 63;
    const int w  = tid >> 6;
    const int wr = w & 1;
    const int wc = w >> 1;
    const int quad = lane >> 4;
    const int lcol = lane & 15;

    f32x4 acc[2][4];
#pragma unroll
    for (int i = 0; i < 2; ++i)
#pragma unroll
        for (int j = 0; j < 4; ++j) acc[i][j] = (f32x4){0.f, 0.f, 0.f, 0.f};

    // A staging: thread covers row ra (0..63), k-quarter qa (16 halves)
    const int ra = tid >> 2, qa = tid & 3;
    const bool fused = (mt < 48);
    const unsigned short *pf, *ps = nullptr;
    if (fused) {
        int g = mt * 64 + ra;                // global binary pair row
        int si = g >> 10, gs = g & 1023;
        int b = gs >> 6, i = (gs >> 3) & 7, j = gs & 7;
        pf = yfb + (long)(si * 128 + b * 8 + i) * 6144;
        ps = ysb + (long)(si * 128 + b * 8 + j) * 6144;
    } else {
        pf = Au + (long)((mt - 48) * 64 + ra) * 6144;
    }
    const unsigned short* Bt = fused ? Btb : Btu;
    const int rb = tid >> 1, hb = tid & 1;
    const long brow = (long)rb * 6144;
    const int kbase0 = kc * 768;

    // ---- prologue: load iter 0 into registers ----
    uint4 rb0, rb1, rb2, rb3, rf0, rf1, rs0, rs1;
    {
        const uint4* gbp = (const uint4*)(Bt + brow + kbase0 + hb * 32);
        rb0 = gbp[0]; rb1 = gbp[1]; rb2 = gbp[2]; rb3 = gbp[3];
        const uint4* gf = (const uint4*)(pf + kbase0 + qa * 16);
        rf0 = gf[0]; rf1 = gf[1];
        if (fused) {
            const uint4* gs2 = (const uint4*)(ps + kbase0 + qa * 16);
            rs0 = gs2[0]; rs1 = gs2[1];
        }
    }

    for (int it = 0; it < 12; ++it) {
        uint4 w0 = rf0, w1 = rf1;
        if (fused) { w0 = pair_relu4(rf0, rs0); w1 = pair_relu4(rf1, rs1); }
        __syncthreads();   // previous iter's LDS reads complete
        {
            uint4* da = (uint4*)(lsA + ra * 72 + qa * 16);
            uint4* db = (uint4*)(lsB + rb * 72 + hb * 32);
            da[0] = w0; da[1] = w1;
            db[0] = rb0; db[1] = rb1; db[2] = rb2; db[3] = rb3;
        }
        __syncthreads();
        // ---- prefetch next iter (overlaps MFMA below) ----
        if (it < 11) {
            const int kb = kbase0 + (it + 1) * 64;
            const uint4* gbp = (const uint4*)(Bt + brow + kb + hb * 32);
            rb0 = gbp[0]; rb1 = gbp[1]; rb2 = gbp[2]; rb3 = gbp[3];
            const uint4* gf = (const uint4*)(pf + kb + qa * 16);
            rf0 = gf[0]; rf1 = gf[1];
            if (fused) {
                const uint4* gs2 = (const uint4*)(ps + kb + qa * 16);
                rs0 = gs2[0]; rs1 = gs2[1];
            }
        }
#pragma unroll
        for (int ks = 0; ks < 2; ++ks) {
            f16x8 af[2], bfr[4];
#pragma unroll
            for (int t = 0; t < 2; ++t)
                af[t] = *(const f16x8*)(lsA + (wr * 32 + t * 16 + lcol) * 72 + ks * 32 + quad * 8);
#pragma unroll
            for (int t = 0; t < 4; ++t)
                bfr[t] = *(const f16x8*)(lsB + (wc * 64 + t * 16 + lcol) * 72 + ks * 32 + quad * 8);
#pragma unroll
            for (int i = 0; i < 2; ++i)
#pragma unroll
                for (int j = 0; j < 4; ++j)
                    acc[i][j] = __builtin_amdgcn_mfma_f32_16x16x32_f16(af[i], bfr[j], acc[i][j], 0, 0, 0);
        }
    }

    __half* op = partial + (long)(kc * 54 + mt) * 8192;
#pragma unroll
    for (int i = 0; i < 2; ++i)
#pragma unroll
        for (int j = 0; j < 4; ++j)
#pragma unroll
            for (int reg = 0; reg < 4; ++reg) {
                int rr = wr * 32 + i * 16 + quad * 4 + reg;
                int cc = wc * 64 + j * 16 + lcol;
                op[rr * 128 + cc] = __float2half(acc[i][j][reg]);
            }
}

// ---------------------------------------------------------------------------
// Kernel 3: fully fused head. One 16-lane group per DESTINATION position:
// resolve source row from n_obj, read 8 split-K partials (f16), bias+relu+FC2
// (shuffle-reduced), gumbel-softmax (2-way -> sigmoid), mask, write d_out.
// Identical to R7 (proven).
// ---------------------------------------------------------------------------
__global__ __launch_bounds__(256) void head_kernel(
    const __half* __restrict__ partial,
    const float* __restrict__ b2b, const float* __restrict__ b2u,
    const float* __restrict__ W3b, const float* __restrict__ b3b,
    const float* __restrict__ W3u, const float* __restrict__ b3u,
    const float* __restrict__ gb, const float* __restrict__ gu,
    const int* __restrict__ nobj, const float* __restrict__ temp_p,
    float* __restrict__ out)
{
    const int tid = threadIdx.x;
    const int dp = blockIdx.x * 16 + (tid >> 4);   // destination position 0..3455
    const int c = tid & 15;
    const bool un = dp >= 3072;

    int srcrow, validf;
    long gidx, oidx;
    if (!un) {
        int si = dp / 1024, rem = dp % 1024;
        int b = rem >> 6, p = rem & 63;
        int n = nobj[b];
        int ns = n > 0 ? n : 1;
        int k = (p / ns) * 8 + (p % ns);
        validf = p < n * n;
        int kk = k < 63 ? k : 63;
        srcrow = si * 1024 + b * 64 + kk;
        gidx = (long)srcrow * 2;                 // gumbel uses SOURCE index
        oidx = (long)si * 2048 + (b * 64 + p) * 2;
    } else {
        int r = dp - 3072;
        int si = r / 128, q = r % 128;
        int b = q >> 3, i = q & 7;
        srcrow = 3072 + r;
        validf = i < nobj[b];
        gidx = (long)si * 256 + q * 2;
        oidx = 6144 + (long)si * 256 + q * 2;
    }

    const float* b2 = un ? b2u : b2b;
    const float* W3 = un ? W3u : W3b;
    const int mt = srcrow >> 6, rr = srcrow & 63;
    float l0 = 0.f, l1 = 0.f;
    for (int f = c; f < 100; f += 16) {
        float s = b2[f];
#pragma unroll
        for (int kc = 0; kc < 8; ++kc)
            s += __half2float(partial[((long)(kc * 54 + mt) * 64 + rr) * 128 + f]);
        float hv = s > 0.f ? s : 0.f;
        l0 = fmaf(hv, W3[f * 2],     l0);
        l1 = fmaf(hv, W3[f * 2 + 1], l1);
    }
#pragma unroll
    for (int off = 8; off >= 1; off >>= 1) {
        l0 += __shfl_xor(l0, off);
        l1 += __shfl_xor(l1, off);
    }
    if (c == 0) {
        const float* b3 = un ? b3u : b3b;
        const float* g = (un ? gu : gb) + gidx;
        float d = ((l0 + b3[0] + g[0]) - (l1 + b3[1] + g[1])) / temp_p[0];
        float p0 = 1.f / (1.f + expf(-d));
        out[oidx]     = validf ? p0 : 0.f;
        out[oidx + 1] = validf ? 1.f - p0 : 0.f;
    }
}

// ---------------------------------------------------------------------------
// Workspace layout (bytes)
// ---------------------------------------------------------------------------
static const size_t YFB_OFF  = 0;                          // 384*6144 f16 = 4,718,592
static const size_t YSB_OFF  = 4718592;                    // 4,718,592
static const size_t AU_OFF   = 9437184;                    // 4,718,592
static const size_t BTB_OFF  = 14155776;                   // 1,572,864
static const size_t BTU_OFF  = 15728640;                   // 1,572,864
static const size_t PART_OFF = 17301504;                   // 8*54*64*128 f16 = 7,077,888
// total = 24,379,392 bytes

extern "C" void kernel_launch(void* const* d_in, const int* in_sizes, int n_in,
                              void* d_out, int out_size, void* d_ws, size_t ws_size,
                              hipStream_t stream) {
    const float* state   = (const float*)d_in[0];
    const float* state_n = (const float*)d_in[1];
    const float* state_t = (const float*)d_in[2];
    const int*   n_obj   = (const int*)  d_in[3];
    const float* temp    = (const float*)d_in[4];
    const float* g_un    = (const float*)d_in[5];
    const float* g_bin   = (const float*)d_in[6];
    const float* Wc_u    = (const float*)d_in[7];
    const float* bc_u    = (const float*)d_in[8];
    const float* W2_u    = (const float*)d_in[9];
    const float* b2_u    = (const float*)d_in[10];
    const float* W3_u    = (const float*)d_in[11];
    const float* b3_u    = (const float*)d_in[12];
    const float* Wc_b    = (const float*)d_in[13];
    const float* bc_b    = (const float*)d_in[14];
    const float* W2_b    = (const float*)d_in[15];
    const float* b2_b    = (const float*)d_in[16];
    const float* W3_b    = (const float*)d_in[17];
    const float* b3_b    = (const float*)d_in[18];

    char* ws = (char*)d_ws;
    unsigned short* yfb  = (unsigned short*)(ws + YFB_OFF);
    unsigned short* ysb  = (unsigned short*)(ws + YSB_OFF);
    unsigned short* Au   = (unsigned short*)(ws + AU_OFF);
    unsigned short* Btb  = (unsigned short*)(ws + BTB_OFF);
    unsigned short* Btu  = (unsigned short*)(ws + BTU_OFF);
    __half*         prt  = (__half*)(ws + PART_OFF);
    float*          out  = (float*)d_out;

    hipLaunchKernelGGL(conv_prep_kernel, dim3(864), dim3(256), 0, stream,
                       state, state_n, state_t, Wc_u, Wc_b, bc_u, bc_b, W2_b, W2_u,
                       Au, yfb, ysb, Btb, Btu);
    hipLaunchKernelGGL(gemm_kernel, dim3(432), dim3(256), 0, stream,
                       yfb, ysb, Au, Btb, Btu, prt);
    hipLaunchKernelGGL(head_kernel, dim3(216), dim3(256), 0, stream,
                       prt, b2_b, b2_u, W3_b, b3_b, W3_u, b3_u,
                       g_bin, g_un, n_obj, temp, out);
}